// Round 4
// baseline (231.262 us; speedup 1.0000x reference)
//
#include <hip/hip_runtime.h>
#include <math.h>

#define D_MODEL 1024
#define RANK    64
#define PMAX    16
#define S_LEN   1024
#define HD      64
#define MROWS   4096   // B*S
#define NHEAD   16
#define BATCH   4

typedef short short8v __attribute__((ext_vector_type(8)));
typedef float floatx4 __attribute__((ext_vector_type(4)));

typedef __attribute__((address_space(1))) const unsigned int* gptr_t;
typedef __attribute__((address_space(3))) unsigned int* lptr_t;

// async global->LDS, 16 bytes per lane (global_load_lds_dwordx4)
static __device__ __forceinline__ void async16(const void* g, void* l) {
    __builtin_amdgcn_global_load_lds((gptr_t)g, (lptr_t)l, 16, 0, 0);
}

// fp32 -> bf16 bits, round-to-nearest-even (finite inputs only)
static __device__ __forceinline__ short f2bf(float f) {
    unsigned int u = __float_as_uint(f);
    u = (u + 0x7fffu + ((u >> 16) & 1u)) >> 16;
    return (short)u;
}

// ---------------------------------------------------------------------------
// Kernel 0: softmax -> top-k -> renormalize (== softmax over selected logits)
// ---------------------------------------------------------------------------
__global__ void topk_weights_kernel(const float* __restrict__ ql,
                                    const float* __restrict__ kl,
                                    const float* __restrict__ vl,
                                    const int* __restrict__ topk,
                                    int* __restrict__ idx_out,     // [3][16]
                                    float* __restrict__ w_out) {   // [3][16]
    int bank = threadIdx.x;
    if (bank >= 3) return;
    const float* lg = (bank == 0) ? ql : (bank == 1) ? kl : vl;
    int K = *topk; if (K < 1) K = 1; if (K > PMAX) K = PMAX;
    float l[PMAX];
    for (int i = 0; i < PMAX; ++i) l[i] = lg[i];
    bool used[PMAX];
    for (int i = 0; i < PMAX; ++i) used[i] = false;
    int   sel_i[PMAX];
    float sel_l[PMAX];
    for (int j = 0; j < K; ++j) {
        int best = -1; float bv = -INFINITY;
        for (int i = 0; i < PMAX; ++i)
            if (!used[i] && l[i] > bv) { bv = l[i]; best = i; }
        used[best] = true; sel_i[j] = best; sel_l[j] = bv;
    }
    float mx = sel_l[0];
    float e[PMAX];
    float sum = 0.f;
    for (int j = 0; j < K; ++j) { e[j] = __expf(sel_l[j] - mx); sum += e[j]; }
    float inv = 1.f / sum;
    for (int j = 0; j < PMAX; ++j) {
        idx_out[bank * PMAX + j] = (j < K) ? sel_i[j] : 0;
        w_out[bank * PMAX + j]   = (j < K) ? e[j] * inv : 0.f;
    }
}

// ---------------------------------------------------------------------------
// elementwise fp32 -> bf16 (vectorized)
// ---------------------------------------------------------------------------
__global__ __launch_bounds__(256) void convert_bf16_kernel(
    const float* __restrict__ src, short* __restrict__ dst, int n4) {
    int i = blockIdx.x * 256 + threadIdx.x;
    if (i < n4) {
        float4 f = ((const float4*)src)[i];
        short4 o;
        o.x = f2bf(f.x); o.y = f2bf(f.y); o.z = f2bf(f.z); o.w = f2bf(f.w);
        ((short4*)dst)[i] = o;
    }
}

// ---------------------------------------------------------------------------
// prep: build B^T-layout bf16 bank matrices.
// ---------------------------------------------------------------------------
__global__ __launch_bounds__(256) void prep_uv_kernel(
    const float* __restrict__ qU, const float* __restrict__ kU,
    const float* __restrict__ vU,
    const float* __restrict__ qV, const float* __restrict__ kV,
    const float* __restrict__ vV,
    const int* __restrict__ idx, const float* __restrict__ wsel,
    short* __restrict__ Ut, short* __restrict__ Vt) {
    int z    = blockIdx.z;     // 0..5
    int j    = blockIdx.y;     // 0..15
    int tile = blockIdx.x;     // 0..15
    int t    = threadIdx.x;
    __shared__ float T[64][65];
    int bank = (z < 3) ? z : z - 3;
    int p = idx[bank * PMAX + j];

    if (z < 3) {
        const float* U = (bank == 0) ? qU : (bank == 1) ? kU : vU;
        const float* src = U + (size_t)p * D_MODEL * RANK;   // [d][r]
        int d0 = tile * 64;
        int rl = t & 63, dq = t >> 6;
#pragma unroll
        for (int i = 0; i < 16; ++i) {
            int dl = i * 4 + dq;
            T[rl][dl] = src[(size_t)(d0 + dl) * RANK + rl];
        }
        __syncthreads();
        short* dst = Ut + (size_t)bank * D_MODEL * D_MODEL;
        int rr = t >> 2;
#pragma unroll
        for (int i = 0; i < 4; ++i) {
            int c = (t & 3) * 16 + i * 4;
            short4 o;
            o.x = f2bf(T[rr][c + 0]); o.y = f2bf(T[rr][c + 1]);
            o.z = f2bf(T[rr][c + 2]); o.w = f2bf(T[rr][c + 3]);
            *(short4*)&dst[(size_t)(j * 64 + rr) * D_MODEL + d0 + c] = o;
        }
    } else {
        const float* V = (bank == 0) ? qV : (bank == 1) ? kV : vV;
        float wj = wsel[bank * PMAX + j];
        const float* src = V + (size_t)p * RANK * D_MODEL;    // [r][n]
        int n0 = tile * 64;
        int nl = t & 63, rq = t >> 6;
#pragma unroll
        for (int i = 0; i < 16; ++i) {
            int rl = i * 4 + rq;
            T[nl][rl] = src[(size_t)rl * D_MODEL + n0 + nl] * wj;
        }
        __syncthreads();
        short* dst = Vt + (size_t)bank * D_MODEL * D_MODEL;
        int rr = t >> 2;
#pragma unroll
        for (int i = 0; i < 4; ++i) {
            int c = (t & 3) * 16 + i * 4;
            short4 o;
            o.x = f2bf(T[rr][c + 0]); o.y = f2bf(T[rr][c + 1]);
            o.z = f2bf(T[rr][c + 2]); o.w = f2bf(T[rr][c + 3]);
            *(short4*)&dst[(size_t)(n0 + rr) * D_MODEL + j * 64 + c] = o;
        }
    }
}

// ---------------------------------------------------------------------------
// m97-style bf16 MFMA GEMM tile body (unchanged from R3)
// ---------------------------------------------------------------------------
static __device__ __forceinline__ void mfma_gemm_tile(
    const short* __restrict__ A, const short* __restrict__ B, int kl,
    int m0, int n0, short* As, short* Bs, floatx4 acc[4][4]) {
    const int t    = threadIdx.x;
    const int w    = t >> 6;
    const int lane = t & 63;
    const int wm   = w & 1, wn = w >> 1;
    const int colL = lane & 15, quad = lane >> 4;
    const int srow  = lane >> 2;
    const int skoff = (lane & 3) * 8;

#pragma unroll
    for (int i = 0; i < 4; ++i)
#pragma unroll
        for (int j = 0; j < 4; ++j) acc[i][j] = (floatx4){0.f, 0.f, 0.f, 0.f};

    for (int k0 = 0; k0 < kl; k0 += 32) {
        async16(A + (size_t)(m0 + w * 16 + srow) * D_MODEL + k0 + skoff,
                As + (w * 16 + srow) * 32 + skoff);
        async16(A + (size_t)(m0 + 64 + w * 16 + srow) * D_MODEL + k0 + skoff,
                As + (64 + w * 16 + srow) * 32 + skoff);
        async16(B + (size_t)(n0 + w * 16 + srow) * D_MODEL + k0 + skoff,
                Bs + (w * 16 + srow) * 32 + skoff);
        async16(B + (size_t)(n0 + 64 + w * 16 + srow) * D_MODEL + k0 + skoff,
                Bs + (64 + w * 16 + srow) * 32 + skoff);
        __syncthreads();
        short8v af[4], bf[4];
#pragma unroll
        for (int i = 0; i < 4; ++i)
            af[i] = *(const short8v*)&As[(wm * 64 + i * 16 + colL) * 32 + quad * 8];
#pragma unroll
        for (int j = 0; j < 4; ++j)
            bf[j] = *(const short8v*)&Bs[(wn * 64 + j * 16 + colL) * 32 + quad * 8];
#pragma unroll
        for (int i = 0; i < 4; ++i)
#pragma unroll
            for (int j = 0; j < 4; ++j)
                acc[i][j] = __builtin_amdgcn_mfma_f32_16x16x32_bf16(af[i], bf[j], acc[i][j], 0, 0, 0);
        __syncthreads();
    }
}

// ---------------------------------------------------------------------------
// Kernel 1: h[bank] = xb @ Ut[bank]^T
// ---------------------------------------------------------------------------
__global__ __launch_bounds__(256) void gemm_h_kernel(
    const short* __restrict__ xb, const short* __restrict__ Ut,
    const int* __restrict__ topk, short* __restrict__ h) {
    int K = *topk; if (K < 1) K = 1; if (K > PMAX) K = PMAX;
    int n0 = blockIdx.y * 128;
    if (n0 >= K * 64) return;
    int m0 = blockIdx.x * 128;
    int bank = blockIdx.z;
    __shared__ short As[128 * 32];
    __shared__ short Bs[128 * 32];
    floatx4 acc[4][4];
    mfma_gemm_tile(xb, Ut + (size_t)bank * D_MODEL * D_MODEL, D_MODEL, m0, n0, As, Bs, acc);

    const int t = threadIdx.x, w = t >> 6, lane = t & 63;
    const int wm = w & 1, wn = w >> 1, colL = lane & 15, quad = lane >> 4;
    short* H = h + (size_t)bank * MROWS * D_MODEL;
#pragma unroll
    for (int i = 0; i < 4; ++i)
#pragma unroll
        for (int j = 0; j < 4; ++j)
#pragma unroll
            for (int r = 0; r < 4; ++r)
                H[(size_t)(m0 + wm * 64 + i * 16 + quad * 4 + r) * D_MODEL +
                  (n0 + wn * 64 + j * 16 + colL)] = f2bf(acc[i][j][r]);
}

// ---------------------------------------------------------------------------
// Kernel 2: qkv[bank] = h[bank] @ Vt[bank]^T -> bf16 [3][B*H][S][D]
// bank 0 (Q) is pre-scaled by 1/sqrt(64)*log2(e) for the attention kernel.
// ---------------------------------------------------------------------------
__global__ __launch_bounds__(256) void gemm_qkv_kernel(
    const short* __restrict__ h, const short* __restrict__ Vt,
    const int* __restrict__ topk, short* __restrict__ qkv) {
    int K = *topk; if (K < 1) K = 1; if (K > PMAX) K = PMAX;
    int m0 = blockIdx.x * 128;
    int n0 = blockIdx.y * 128;
    int bank = blockIdx.z;
    __shared__ short As[128 * 32];
    __shared__ short Bs[128 * 32];
    floatx4 acc[4][4];
    mfma_gemm_tile(h + (size_t)bank * MROWS * D_MODEL,
                   Vt + (size_t)bank * D_MODEL * D_MODEL, K * 64, m0, n0, As, Bs, acc);

    const int t = threadIdx.x, w = t >> 6, lane = t & 63;
    const int wm = w & 1, wn = w >> 1, colL = lane & 15, quad = lane >> 4;
    short* outp = qkv + (size_t)bank * MROWS * D_MODEL;
    const float scl = (bank == 0) ? 0.18033688f : 1.0f;   // 0.125 * log2(e)
#pragma unroll
    for (int i = 0; i < 4; ++i)
#pragma unroll
        for (int j = 0; j < 4; ++j)
#pragma unroll
            for (int r = 0; r < 4; ++r) {
                int m = m0 + wm * 64 + i * 16 + quad * 4 + r;
                int n = n0 + wn * 64 + j * 16 + colL;
                int b = m >> 10, s = m & 1023;
                int head = n >> 6, d = n & 63;
                outp[(((size_t)(b * NHEAD + head) << 10) + s) * HD + d] = f2bf(acc[i][j][r] * scl);
            }
}

// ---------------------------------------------------------------------------
// transpose V bank: [bh][s][64] -> [bh][64][1024]  (per-head V^T)
// ---------------------------------------------------------------------------
__global__ __launch_bounds__(256) void transpose_v_kernel(
    const short* __restrict__ src, short* __restrict__ dst) {
    int st = blockIdx.x, bh = blockIdx.y;
    __shared__ short T[64][72];
    const short* S = src + (size_t)bh * (S_LEN * HD) + (size_t)st * 64 * HD;
    int r = threadIdx.x >> 2, i = threadIdx.x & 3;
    *(short8v*)&T[r][i * 16]     = *(const short8v*)&S[r * HD + i * 16];
    *(short8v*)&T[r][i * 16 + 8] = *(const short8v*)&S[r * HD + i * 16 + 8];
    __syncthreads();
    short* Drow = dst + (size_t)bh * (S_LEN * HD) + (size_t)r * S_LEN + st * 64 + i * 16;
    short8v o0, o1;
#pragma unroll
    for (int k = 0; k < 8; ++k) o0[k] = T[i * 16 + k][r];
#pragma unroll
    for (int k = 0; k < 8; ++k) o1[k] = T[i * 16 + 8 + k][r];
    *(short8v*)&Drow[0] = o0;
    *(short8v*)&Drow[8] = o1;
}

// ---------------------------------------------------------------------------
// Kernel 3: causal flash attention, bf16 MFMA, double-buffered async staging.
// K LDS layout: unpadded 64x64 with XOR chunk swizzle (chunk i ^ (row&7)).
// ---------------------------------------------------------------------------
static __device__ __forceinline__ void stage_tiles(
    const short* __restrict__ Kg, const short* __restrict__ Vg, int jt,
    short* KsB, short* VsB, int w, int lane) {
#pragma unroll
    for (int q = 0; q < 2; ++q) {
        int c   = q * 64 + lane;
        int r16 = c >> 3;
        int i   = c & 7;
        int r   = w * 16 + r16;
        int g   = i ^ (r16 & 7);
        async16(Kg + (size_t)(jt * 64 + r) * HD + g * 8, KsB + r * 64 + i * 8);
        async16(Vg + (size_t)r * S_LEN + jt * 64 + g * 8, VsB + r * 64 + i * 8);
    }
}

template<bool DIAG>
static __device__ __forceinline__ void attn_step(
    const short* KsB, const short* VsB, short* Pw,
    short8v aq0, short8v aq1, int w, int col, int quad,
    floatx4& O0, floatx4& O1, floatx4& O2, floatx4& O3,
    float mrow[4], float lrow[4]) {
    const int colLow = col & 7;
    floatx4 c4[4];
#pragma unroll
    for (int n = 0; n < 4; ++n) {
        if (!DIAG || n <= w) {
            floatx4 z = {0.f, 0.f, 0.f, 0.f};
            short8v b0 = *(const short8v*)&KsB[(n * 16 + col) * 64 + ((quad ^ colLow) << 3)];
            short8v b1 = *(const short8v*)&KsB[(n * 16 + col) * 64 + (((quad + 4) ^ colLow) << 3)];
            z = __builtin_amdgcn_mfma_f32_16x16x32_bf16(aq0, b0, z, 0, 0, 0);
            z = __builtin_amdgcn_mfma_f32_16x16x32_bf16(aq1, b1, z, 0, 0, 0);
            if (DIAG) {
#pragma unroll
                for (int r = 0; r < 4; ++r)
                    if (n == w && col > quad * 4 + r) z[r] = -INFINITY;
            }
            c4[n] = z;
        } else {
            c4[n] = (floatx4){-INFINITY, -INFINITY, -INFINITY, -INFINITY};
        }
    }
#pragma unroll
    for (int r = 0; r < 4; ++r) {
        float tm = fmaxf(fmaxf(c4[0][r], c4[1][r]), fmaxf(c4[2][r], c4[3][r]));
        tm = fmaxf(tm, __shfl_xor(tm, 1));
        tm = fmaxf(tm, __shfl_xor(tm, 2));
        tm = fmaxf(tm, __shfl_xor(tm, 4));
        tm = fmaxf(tm, __shfl_xor(tm, 8));
        float mnew  = fmaxf(mrow[r], tm);
        float alpha = exp2f(mrow[r] - mnew);
        float p0 = exp2f(c4[0][r] - mnew), p1 = exp2f(c4[1][r] - mnew);
        float p2 = exp2f(c4[2][r] - mnew), p3 = exp2f(c4[3][r] - mnew);
        lrow[r] = lrow[r] * alpha + (p0 + p1 + p2 + p3);   // per-lane partial
        mrow[r] = mnew;
        O0[r] *= alpha; O1[r] *= alpha; O2[r] *= alpha; O3[r] *= alpha;
        short* pr = Pw + (quad * 4 + r) * 72 + col;
        pr[0]  = f2bf(p0); pr[16] = f2bf(p1);
        pr[32] = f2bf(p2); pr[48] = f2bf(p3);
    }
    const int ksmax = DIAG ? (w >> 1) : 1;
#pragma unroll
    for (int ks = 0; ks < 2; ++ks) {
        if (ks > ksmax) break;
        short8v ap = *(const short8v*)&Pw[col * 72 + ks * 32 + quad * 8];
        int pc = ((ks * 4 + quad) ^ colLow) << 3;
        short8v v0 = *(const short8v*)&VsB[(0  + col) * 64 + pc];
        short8v v1 = *(const short8v*)&VsB[(16 + col) * 64 + pc];
        short8v v2 = *(const short8v*)&VsB[(32 + col) * 64 + pc];
        short8v v3 = *(const short8v*)&VsB[(48 + col) * 64 + pc];
        O0 = __builtin_amdgcn_mfma_f32_16x16x32_bf16(ap, v0, O0, 0, 0, 0);
        O1 = __builtin_amdgcn_mfma_f32_16x16x32_bf16(ap, v1, O1, 0, 0, 0);
        O2 = __builtin_amdgcn_mfma_f32_16x16x32_bf16(ap, v2, O2, 0, 0, 0);
        O3 = __builtin_amdgcn_mfma_f32_16x16x32_bf16(ap, v3, O3, 0, 0, 0);
    }
}

__global__ __launch_bounds__(256) void attn_mfma_kernel(
    const short* __restrict__ qkv,    // Q/K: bf16 [bank][bh][s][64] (Q pre-scaled)
    const short* __restrict__ vtb,    // V^T: bf16 [bh][64][1024]
    short* __restrict__ attn_out) {   // bf16 [B][S][H*D]
    const int t    = threadIdx.x;
    const int w    = t >> 6;
    const int lane = t & 63;
    const int col  = lane & 15;
    const int quad = lane >> 4;
    const int pr   = blockIdx.x;   // 0..7
    const int bh   = blockIdx.y;   // 0..63
    const size_t HS   = (size_t)S_LEN * HD;
    const size_t BSTR = (size_t)MROWS * D_MODEL;
    const short* Qg = qkv + (size_t)bh * HS;
    const short* Kg = qkv + BSTR + (size_t)bh * HS;
    const short* Vg = vtb + (size_t)bh * HS;

    __shared__ short Ks[2][4096];
    __shared__ short Vs[2][4096];
    __shared__ short Ps[4][16 * 72];
    short* Pw = &Ps[w][0];

    for (int ph = 0; ph < 2; ++ph) {
        const int qt = ph ? (15 - pr) : pr;
        const int qrow = qt * 64 + w * 16 + col;
        short8v aq0 = *(const short8v*)(Qg + (size_t)qrow * HD + quad * 8);
        short8v aq1 = *(const short8v*)(Qg + (size_t)qrow * HD + 32 + quad * 8);
        floatx4 O0 = {0.f, 0.f, 0.f, 0.f}, O1 = O0, O2 = O0, O3 = O0;
        float mrow[4] = {-INFINITY, -INFINITY, -INFINITY, -INFINITY};
        float lrow[4] = {0.f, 0.f, 0.f, 0.f};

        __syncthreads();                       // prior phase readers done
        stage_tiles(Kg, Vg, 0, Ks[0], Vs[0], w, lane);
        __syncthreads();                       // tile 0 resident
        int cur = 0;
        for (int jt = 0; jt < qt; ++jt) {
            stage_tiles(Kg, Vg, jt + 1, Ks[cur ^ 1], Vs[cur ^ 1], w, lane);
            attn_step<false>(Ks[cur], Vs[cur], Pw, aq0, aq1, w, col, quad,
                             O0, O1, O2, O3, mrow, lrow);
            __syncthreads();                   // drains prefetch, frees cur
            cur ^= 1;
        }
        attn_step<true>(Ks[cur], Vs[cur], Pw, aq0, aq1, w, col, quad,
                        O0, O1, O2, O3, mrow, lrow);

        // ---- epilogue: reduce l across the 16 cols, normalize, store bf16 ----
        const int b  = bh >> 4;
        const int hh = bh & 15;
        short* orow = attn_out +
            ((size_t)(b * S_LEN) + qt * 64 + w * 16) * D_MODEL + hh * 64;
#pragma unroll
        for (int r = 0; r < 4; ++r) {
            float l = lrow[r];
            l += __shfl_xor(l, 1); l += __shfl_xor(l, 2);
            l += __shfl_xor(l, 4); l += __shfl_xor(l, 8);
            float inv = 1.f / l;
            short* prw = orow + (size_t)(quad * 4 + r) * D_MODEL;
            prw[0  + col] = f2bf(O0[r] * inv);
            prw[16 + col] = f2bf(O1[r] * inv);
            prw[32 + col] = f2bf(O2[r] * inv);
            prw[48 + col] = f2bf(O3[r] * inv);
        }
    }
}

// ---------------------------------------------------------------------------
// Kernel 4: out = attn(bf16) @ out_w(bf16)^T -> fp32 d_out
// ---------------------------------------------------------------------------
__global__ __launch_bounds__(256) void gemm_proj_kernel(
    const short* __restrict__ attnb, const short* __restrict__ wb,
    float* __restrict__ outp) {
    int m0 = blockIdx.x * 128;
    int n0 = blockIdx.y * 128;
    __shared__ short As[128 * 32];
    __shared__ short Bs[128 * 32];
    floatx4 acc[4][4];
    mfma_gemm_tile(attnb, wb, D_MODEL, m0, n0, As, Bs, acc);

    const int t = threadIdx.x, w = t >> 6, lane = t & 63;
    const int wm = w & 1, wn = w >> 1, colL = lane & 15, quad = lane >> 4;
#pragma unroll
    for (int i = 0; i < 4; ++i)
#pragma unroll
        for (int j = 0; j < 4; ++j)
#pragma unroll
            for (int r = 0; r < 4; ++r)
                outp[(size_t)(m0 + wm * 64 + i * 16 + quad * 4 + r) * D_MODEL +
                     (n0 + wn * 64 + j * 16 + colL)] = acc[i][j][r];
}

// ---------------------------------------------------------------------------
extern "C" void kernel_launch(void* const* d_in, const int* in_sizes, int n_in,
                              void* d_out, int out_size, void* d_ws, size_t ws_size,
                              hipStream_t stream) {
    const float* x    = (const float*)d_in[0];
    const float* qU   = (const float*)d_in[1];
    const float* qV   = (const float*)d_in[2];
    const float* kU   = (const float*)d_in[3];
    const float* kV   = (const float*)d_in[4];
    const float* vU   = (const float*)d_in[5];
    const float* vV   = (const float*)d_in[6];
    const float* qlg  = (const float*)d_in[7];
    const float* klg  = (const float*)d_in[8];
    const float* vlg  = (const float*)d_in[9];
    const float* outw = (const float*)d_in[10];
    const int*   topk = (const int*)d_in[11];
    float* outp = (float*)d_out;

    char* ws = (char*)d_ws;
    int*   idxp = (int*)ws;                              // [3][16]
    float* wp   = (float*)(ws + 256);                    // [3][16]
    short* xb   = (short*)(ws + 512);                    // 8 MB
    short* Ut   = xb + (size_t)MROWS * D_MODEL;          // 6 MB
    short* Vt   = Ut + (size_t)3 * D_MODEL * D_MODEL;    // 6 MB
    short* wb   = Vt + (size_t)3 * D_MODEL * D_MODEL;    // 2 MB
    short* hbuf = wb + (size_t)D_MODEL * D_MODEL;        // 24 MB
    short* qkvb = hbuf + (size_t)3 * MROWS * D_MODEL;    // 24 MB
    short* attnb = qkvb + (size_t)3 * MROWS * D_MODEL;   // 8 MB
    short* vtb  = attnb + (size_t)MROWS * D_MODEL;       // 8 MB

    topk_weights_kernel<<<1, 64, 0, stream>>>(qlg, klg, vlg, topk, idxp, wp);
    convert_bf16_kernel<<<(MROWS * D_MODEL / 4 + 255) / 256, 256, 0, stream>>>(
        x, xb, MROWS * D_MODEL / 4);
    convert_bf16_kernel<<<(D_MODEL * D_MODEL / 4 + 255) / 256, 256, 0, stream>>>(
        outw, wb, D_MODEL * D_MODEL / 4);
    prep_uv_kernel<<<dim3(16, 16, 6), 256, 0, stream>>>(
        qU, kU, vU, qV, kV, vV, idxp, wp, Ut, Vt);
    gemm_h_kernel<<<dim3(32, 8, 3), 256, 0, stream>>>(xb, Ut, topk, hbuf);
    gemm_qkv_kernel<<<dim3(32, 8, 3), 256, 0, stream>>>(hbuf, Vt, topk, qkvb);
    transpose_v_kernel<<<dim3(16, 64), 256, 0, stream>>>(
        qkvb + (size_t)2 * MROWS * D_MODEL, vtb);
    attn_mfma_kernel<<<dim3(8, 64), 256, 0, stream>>>(qkvb, vtb, attnb);
    gemm_proj_kernel<<<dim3(32, 8), 256, 0, stream>>>(attnb, wb, outp);
}